// Round 17
// baseline (186.836 us; speedup 1.0000x reference)
//
#include <hip/hip_runtime.h>

#define TT 512
#define CH 16
#define NCH 32            // 512/16 chunks
#define NPH (NCH + 3)     // A leads; C:W2 trails 1; B trails 2; C:dense trails 3
#define LOG2E 1.44269504088896340736f

typedef float f2 __attribute__((ext_vector_type(2)));

template <int N>
__device__ __forceinline__ int rorki_(int v) {           // row_ror:N (16-lane rows)
    return __builtin_amdgcn_update_dpp(v, v, 0x120 + N, 0xf, 0xf, true);
}
template <int N>
__device__ __forceinline__ float rorkf_(float v) { return __int_as_float(rorki_<N>(__float_as_int(v))); }
template <int C>
__device__ __forceinline__ float shrf_(float v) {        // row_shr:N, shifted-in -> 0
    return __int_as_float(__builtin_amdgcn_update_dpp(0, __float_as_int(v), C, 0xf, 0xf, true));
}
__device__ __forceinline__ float sgm_(float v) {         // sigmoid, arg pre-scaled by log2e
    return __builtin_amdgcn_rcpf(1.f + __builtin_amdgcn_exp2f(-v));
}
__device__ __forceinline__ f2 pfma_(f2 a, f2 b, f2 c) {  // v_pk_fma_f32
    return __builtin_elementwise_fma(a, b, c);
}

__launch_bounds__(192)
__attribute__((amdgpu_waves_per_eu(3, 3)))   // 3 waves/EU -> ~170-VGPR budget
__global__ void gru_3w(const float* __restrict__ x,
                       const float* __restrict__ W1, const float* __restrict__ Ur1,
                       const float* __restrict__ b1,
                       const float* __restrict__ W2, const float* __restrict__ Ur2,
                       const float* __restrict__ b2,
                       const float* __restrict__ Wd, const float* __restrict__ bd,
                       const float* __restrict__ Wo, const float* __restrict__ bo,
                       float* __restrict__ out)
{
    __shared__ float h1b[2][CH][4][8];          //  4 KB  A -> C
    __shared__ float h2b[2][CH][4][16];         //  8 KB  B -> C(dense)
    __shared__ float w2p[2][3][CH][4][16];      // 24 KB  C -> B  (za,ra,hb planes)

    const int tid  = threadIdx.x;
    const int wv   = tid >> 6;          // 0: GRU1, 1: GRU2, 2: W2+dense
    const int lane = tid & 63;
    const int g    = lane >> 4;         // row group (4 rows/block)
    const int j    = lane & 15;
    const int u1   = j & 7;
    const int hi   = j >> 3;
    const int gcol = u1 + 8 * hi;
    const bool ishi = (hi != 0);
    const bool isw  = (j == 15);

    // ---- trace the ror:k permutation (layout-proof rotation weight order) ----
    int Lk[16];
    Lk[0]  = j;
    Lk[1]  = rorki_<1>(j);   Lk[2]  = rorki_<2>(j);   Lk[3]  = rorki_<3>(j);
    Lk[4]  = rorki_<4>(j);   Lk[5]  = rorki_<5>(j);   Lk[6]  = rorki_<6>(j);
    Lk[7]  = rorki_<7>(j);   Lk[8]  = rorki_<8>(j);   Lk[9]  = rorki_<9>(j);
    Lk[10] = rorki_<10>(j);  Lk[11] = rorki_<11>(j);  Lk[12] = rorki_<12>(j);
    Lk[13] = rorki_<13>(j);  Lk[14] = rorki_<14>(j);  Lk[15] = rorki_<15>(j);

    if (wv == 0) {
        // ================= wave A: GRU1 (in-register, R15-proven body) =========
        f2 Gx[4], Hx[4], VC[4], VQ[4];
#pragma unroll
        for (int k = 0; k < 4; ++k) {
            const int a = Lk[2 * k] & 7, b = Lk[2 * k + 1] & 7;
            Gx[k] = f2{LOG2E * W1[a * 24 + gcol],  LOG2E * W1[b * 24 + gcol]};
            Hx[k] = f2{W1[a * 24 + 16 + u1],       W1[b * 24 + 16 + u1]};
            VC[k] = f2{LOG2E * Ur1[a * 24 + gcol], LOG2E * Ur1[b * 24 + gcol]};
            VQ[k] = f2{Ur1[a * 24 + 16 + u1],      Ur1[b * 24 + 16 + u1]};
        }
        const float bAzr = LOG2E * (b1[gcol] + b1[24 + gcol]);
        const float bGh  = b1[16 + u1];
        const float bIh  = b1[40 + u1];

        const float* xbase = x + (size_t)blockIdx.x * 4 * TT * 8;
        const int    xoff  = g * TT * 8 + u1;

        float h1own = 0.f, azrP = bAzr, ihP = bIh;
        float xA = xbase[0 * 8 + xoff];
        float xB = xbase[1 * 8 + xoff];
        float xC = xbase[2 * 8 + xoff];

#define G1STEP(TG, SL, XCUR, XFILL)                                          \
    {                                                                        \
        const float x0 = XCUR;                                               \
        const f2 xp0 = f2{x0,            rorkf_<1>(x0)};                     \
        const f2 xp1 = f2{rorkf_<2>(x0), rorkf_<3>(x0)};                     \
        const f2 xp2 = f2{rorkf_<4>(x0), rorkf_<5>(x0)};                     \
        const f2 xp3 = f2{rorkf_<6>(x0), rorkf_<7>(x0)};                     \
        f2 axp = f2{azrP, 0.f}, ghp = f2{bGh, 0.f};                          \
        axp = pfma_(xp0, Gx[0], axp);  ghp = pfma_(xp0, Hx[0], ghp);         \
        axp = pfma_(xp1, Gx[1], axp);  ghp = pfma_(xp1, Hx[1], ghp);         \
        axp = pfma_(xp2, Gx[2], axp);  ghp = pfma_(xp2, Hx[2], ghp);         \
        axp = pfma_(xp3, Gx[3], axp);  ghp = pfma_(xp3, Hx[3], ghp);         \
        XFILL = xbase[(((TG) + 3) & (TT - 1)) * 8 + xoff];                   \
        const float azrC = axp.x + axp.y;                                    \
        const float s_own = sgm_(azrC);                                      \
        const float s_sw  = rorkf_<8>(s_own);                                \
        const float z1 = ishi ? s_sw : s_own;                                \
        const float r1 = ishi ? s_own : s_sw;                                \
        const float hh1 = fmaxf(fmaf(r1, ihP, ghp.x + ghp.y), 0.f);          \
        h1own = fmaf(z1, h1own - hh1, hh1);                                  \
        const float n0 = h1own;                                              \
        const f2 np0 = f2{n0,            rorkf_<1>(n0)};                     \
        const f2 np1 = f2{rorkf_<2>(n0), rorkf_<3>(n0)};                     \
        const f2 np2 = f2{rorkf_<4>(n0), rorkf_<5>(n0)};                     \
        const f2 np3 = f2{rorkf_<6>(n0), rorkf_<7>(n0)};                     \
        f2 aNp = f2{bAzr, 0.f}, iNp = f2{bIh, 0.f};                          \
        aNp = pfma_(np0, VC[0], aNp);  iNp = pfma_(np0, VQ[0], iNp);         \
        aNp = pfma_(np1, VC[1], aNp);  iNp = pfma_(np1, VQ[1], iNp);         \
        aNp = pfma_(np2, VC[2], aNp);  iNp = pfma_(np2, VQ[2], iNp);         \
        aNp = pfma_(np3, VC[3], aNp);  iNp = pfma_(np3, VQ[3], iNp);         \
        azrP = aNp.x + aNp.y;  ihP = iNp.x + iNp.y;                          \
        h1b[p & 1][SL][g][u1] = h1own;                                       \
    }

        for (int p = 0; p < NPH; ++p) {
            if (p < NCH) {
                const int t0 = p * CH;
                for (int s = 0; s < CH; s += 4) {
                    G1STEP(t0 + s + 0, s + 0, xA, xA)
                    G1STEP(t0 + s + 1, s + 1, xB, xB)
                    G1STEP(t0 + s + 2, s + 2, xC, xC)
                    G1STEP(t0 + s + 3, s + 3, xA, xA)
                    { float t = xB; xB = xC; xC = xA; xA = t; }
                }
            }
            __syncthreads();
        }
#undef G1STEP
    } else if (wv == 1) {
        // ================= wave B: GRU2 core (h2-fan + sigmoid; W2 part from LDS) ==
        f2 Pz[8], Pr[8], Ph[8];                 // h2 fan, rotation-ordered
#pragma unroll
        for (int k = 0; k < 8; ++k) {
            const int a = Lk[2 * k], b = Lk[2 * k + 1];
            Pz[k] = f2{LOG2E * Ur2[a * 48 + j],      LOG2E * Ur2[b * 48 + j]};
            Pr[k] = f2{LOG2E * Ur2[a * 48 + 16 + j], LOG2E * Ur2[b * 48 + 16 + j]};
            Ph[k] = f2{Ur2[a * 48 + 32 + j],         Ur2[b * 48 + 32 + j]};
        }
        const float bA2 = LOG2E * (b2[j] + b2[48 + j]);
        const float bB2 = LOG2E * (b2[16 + j] + b2[64 + j]);
        const float bC2 = b2[80 + j];

        float h2own = 0.f;
        float zaPc, raPc, hbPc, zaPn, raPn, hbPn;   // w2p trio ping-pong

#define G2STEP(SL, ZAC, RAC, HBC, ZAN, RAN, HBN, SN)                         \
    {                                                                        \
        const float h0 = h2own;                                              \
        const f2 tp0 = f2{h0,             rorkf_<1>(h0)};                    \
        const f2 tp1 = f2{rorkf_<2>(h0),  rorkf_<3>(h0)};                    \
        const f2 tp2 = f2{rorkf_<4>(h0),  rorkf_<5>(h0)};                    \
        const f2 tp3 = f2{rorkf_<6>(h0),  rorkf_<7>(h0)};                    \
        const f2 tp4 = f2{rorkf_<8>(h0),  rorkf_<9>(h0)};                    \
        const f2 tp5 = f2{rorkf_<10>(h0), rorkf_<11>(h0)};                   \
        const f2 tp6 = f2{rorkf_<12>(h0), rorkf_<13>(h0)};                   \
        const f2 tp7 = f2{rorkf_<14>(h0), rorkf_<15>(h0)};                   \
        f2 zaA = f2{bA2, 0.f}, raA = f2{bB2, 0.f}, haA = f2{bC2, 0.f};       \
        f2 zaB = f2{0.f, 0.f}, raB = f2{0.f, 0.f}, haB = f2{0.f, 0.f};       \
        zaA = pfma_(tp0, Pz[0], zaA); raA = pfma_(tp0, Pr[0], raA); haA = pfma_(tp0, Ph[0], haA); \
        zaA = pfma_(tp1, Pz[1], zaA); raA = pfma_(tp1, Pr[1], raA); haA = pfma_(tp1, Ph[1], haA); \
        zaA = pfma_(tp2, Pz[2], zaA); raA = pfma_(tp2, Pr[2], raA); haA = pfma_(tp2, Ph[2], haA); \
        zaA = pfma_(tp3, Pz[3], zaA); raA = pfma_(tp3, Pr[3], raA); haA = pfma_(tp3, Ph[3], haA); \
        zaB = pfma_(tp4, Pz[4], zaB); raB = pfma_(tp4, Pr[4], raB); haB = pfma_(tp4, Ph[4], haB); \
        zaB = pfma_(tp5, Pz[5], zaB); raB = pfma_(tp5, Pr[5], raB); haB = pfma_(tp5, Ph[5], haB); \
        zaB = pfma_(tp6, Pz[6], zaB); raB = pfma_(tp6, Pr[6], raB); haB = pfma_(tp6, Ph[6], haB); \
        zaB = pfma_(tp7, Pz[7], zaB); raB = pfma_(tp7, Pr[7], raB); haB = pfma_(tp7, Ph[7], haB); \
        ZAN = w2p[par][0][SN][g][j];                                         \
        RAN = w2p[par][1][SN][g][j];                                         \
        HBN = w2p[par][2][SN][g][j];                                         \
        const f2 zs = zaA + zaB, rs = raA + raB, hs = haA + haB;             \
        const float z2 = sgm_(zs.x + zs.y + ZAC);                            \
        const float r2 = sgm_(rs.x + rs.y + RAC);                            \
        const float hh2 = fmaxf(fmaf(r2, hs.x + hs.y, HBC), 0.f);            \
        h2own = fmaf(z2, h2own - hh2, hh2);                                  \
        h2b[par][SL][g][j] = h2own;                                          \
    }

        for (int p = 0; p < NPH; ++p) {
            if (p >= 2 && p <= NCH + 1) {
                const int par = (p - 2) & 1;
                zaPc = w2p[par][0][0][g][j];
                raPc = w2p[par][1][0][g][j];
                hbPc = w2p[par][2][0][g][j];
                for (int s = 0; s < CH; s += 2) {
                    G2STEP(s + 0, zaPc, raPc, hbPc, zaPn, raPn, hbPn, s + 1)
                    G2STEP(s + 1, zaPn, raPn, hbPn, zaPc, raPc, hbPc, (s + 2) & (CH - 1))
                }
            }
            __syncthreads();
        }
#undef G2STEP
    } else {
        // ================= wave C: W2·h1 partials (+bD2) and dense =============
        f2 Vz[4], Vr[4], Vh[4];                 // W2 taps, NATURAL order
#pragma unroll
        for (int k = 0; k < 4; ++k) {
            Vz[k] = f2{LOG2E * W2[(2 * k) * 48 + j],      LOG2E * W2[(2 * k + 1) * 48 + j]};
            Vr[k] = f2{LOG2E * W2[(2 * k) * 48 + 16 + j], LOG2E * W2[(2 * k + 1) * 48 + 16 + j]};
            Vh[k] = f2{W2[(2 * k) * 48 + 32 + j],         W2[(2 * k + 1) * 48 + 32 + j]};
        }
        f2 Pd[8];                               // dense taps, NATURAL order
#pragma unroll
        for (int k = 0; k < 8; ++k)
            Pd[k] = f2{Wd[(2 * k) * 16 + j], Wd[(2 * k + 1) * 16 + j]};
        const float bD2 = b2[32 + j];
        const float bdj = bd[j], woj = Wo[j], boo = bo[0];
        float* outrow = out + (size_t)(blockIdx.x * 4 + g) * TT;

        float4 kA0, kA1, kB0, kB1;              // h1 ping-pong
        float4 hA0, hA1, hA2, hA3, hB0, hB1, hB2, hB3;   // h2 ping-pong

#define W2STEP(SL, K0, K1, M0, M1, SN)                                       \
    {                                                                        \
        const f2 q0 = f2{K0.x, K0.y}, q1 = f2{K0.z, K0.w};                   \
        const f2 q2 = f2{K1.x, K1.y}, q3 = f2{K1.z, K1.w};                   \
        f2 zp = f2{0.f, 0.f}, rp = f2{0.f, 0.f}, hp = f2{bD2, 0.f};          \
        zp = pfma_(q0, Vz[0], zp); rp = pfma_(q0, Vr[0], rp); hp = pfma_(q0, Vh[0], hp); \
        zp = pfma_(q1, Vz[1], zp); rp = pfma_(q1, Vr[1], rp); hp = pfma_(q1, Vh[1], hp); \
        zp = pfma_(q2, Vz[2], zp); rp = pfma_(q2, Vr[2], rp); hp = pfma_(q2, Vh[2], hp); \
        zp = pfma_(q3, Vz[3], zp); rp = pfma_(q3, Vr[3], rp); hp = pfma_(q3, Vh[3], hp); \
        M0 = *(const float4*)&h1b[parw][SN][g][0];                           \
        M1 = *(const float4*)&h1b[parw][SN][g][4];                           \
        w2p[parw][0][SL][g][j] = zp.x + zp.y;                                \
        w2p[parw][1][SL][g][j] = rp.x + rp.y;                                \
        w2p[parw][2][SL][g][j] = hp.x + hp.y;                                \
    }

#define DSTEP(DL, C0, C1, C2, C3, N0, N1, N2, N3, DN)                        \
    {                                                                        \
        f2 da = f2{bdj, 0.f};                                                \
        da = pfma_(f2{C0.x, C0.y}, Pd[0], da);                               \
        da = pfma_(f2{C0.z, C0.w}, Pd[1], da);                               \
        da = pfma_(f2{C1.x, C1.y}, Pd[2], da);                               \
        da = pfma_(f2{C1.z, C1.w}, Pd[3], da);                               \
        da = pfma_(f2{C2.x, C2.y}, Pd[4], da);                               \
        da = pfma_(f2{C2.z, C2.w}, Pd[5], da);                               \
        da = pfma_(f2{C3.x, C3.y}, Pd[6], da);                               \
        da = pfma_(f2{C3.z, C3.w}, Pd[7], da);                               \
        N0 = *(const float4*)&h2b[pard][DN][g][0];                           \
        N1 = *(const float4*)&h2b[pard][DN][g][4];                           \
        N2 = *(const float4*)&h2b[pard][DN][g][8];                           \
        N3 = *(const float4*)&h2b[pard][DN][g][12];                          \
        float e = fmaxf(da.x + da.y, 0.f) * woj;                             \
        e += shrf_<0x118>(e);                                                \
        e += shrf_<0x114>(e);                                                \
        e += shrf_<0x112>(e);                                                \
        e += shrf_<0x111>(e);                                                \
        if (isw) outd[DL] = e + boo;                                         \
    }

        for (int p = 0; p < NPH; ++p) {
            const bool doW = (p >= 1 && p <= NCH);
            const bool doD = (p >= 3 && p <= NCH + 2);
            const int parw = (p - 1) & 1;
            const int pard = (p - 3) & 1;
            float* outd = outrow + (p - 3) * CH;
            if (doW) {
                kA0 = *(const float4*)&h1b[parw][0][g][0];
                kA1 = *(const float4*)&h1b[parw][0][g][4];
            }
            if (doD) {
                hA0 = *(const float4*)&h2b[pard][0][g][0];
                hA1 = *(const float4*)&h2b[pard][0][g][4];
                hA2 = *(const float4*)&h2b[pard][0][g][8];
                hA3 = *(const float4*)&h2b[pard][0][g][12];
            }
            if (doW && doD) {
                for (int s = 0; s < CH; s += 2) {
                    W2STEP(s + 0, kA0, kA1, kB0, kB1, s + 1)
                    DSTEP(s + 0, hA0, hA1, hA2, hA3, hB0, hB1, hB2, hB3, s + 1)
                    W2STEP(s + 1, kB0, kB1, kA0, kA1, (s + 2) & (CH - 1))
                    DSTEP(s + 1, hB0, hB1, hB2, hB3, hA0, hA1, hA2, hA3, (s + 2) & (CH - 1))
                }
            } else if (doW) {
                for (int s = 0; s < CH; s += 2) {
                    W2STEP(s + 0, kA0, kA1, kB0, kB1, s + 1)
                    W2STEP(s + 1, kB0, kB1, kA0, kA1, (s + 2) & (CH - 1))
                }
            } else if (doD) {
                for (int s = 0; s < CH; s += 2) {
                    DSTEP(s + 0, hA0, hA1, hA2, hA3, hB0, hB1, hB2, hB3, s + 1)
                    DSTEP(s + 1, hB0, hB1, hB2, hB3, hA0, hA1, hA2, hA3, (s + 2) & (CH - 1))
                }
            }
            __syncthreads();
        }
#undef W2STEP
#undef DSTEP
    }
}

extern "C" void kernel_launch(void* const* d_in, const int* in_sizes, int n_in,
                              void* d_out, int out_size, void* d_ws, size_t ws_size,
                              hipStream_t stream) {
    const float* x   = (const float*)d_in[0];
    const float* W1  = (const float*)d_in[1];
    const float* Ur1 = (const float*)d_in[2];
    const float* b1  = (const float*)d_in[3];
    const float* W2  = (const float*)d_in[4];
    const float* Ur2 = (const float*)d_in[5];
    const float* b2  = (const float*)d_in[6];
    const float* Wd  = (const float*)d_in[7];
    const float* bd  = (const float*)d_in[8];
    const float* Wo  = (const float*)d_in[9];
    const float* bo  = (const float*)d_in[10];
    float* out = (float*)d_out;

    dim3 grid(4096 / 4);   // 1024 blocks x 3 waves = 3072 waves = 3/SIMD
    dim3 block(192);       // wave 0: GRU1, wave 1: GRU2, wave 2: W2+dense
    gru_3w<<<grid, block, 0, stream>>>(x, W1, Ur1, b1, W2, Ur2, b2,
                                       Wd, bd, Wo, bo, out);
}

// Round 18
// 164.926 us; speedup vs baseline: 1.1329x; 1.1329x over previous
//
#include <hip/hip_runtime.h>

#define TT 512
#define CH 32
#define NCH 16            // 512/32 chunks
#define NPH (NCH + 2)     // phases: A leads, dense trails by 2
#define LOG2E 1.44269504088896340736f

typedef float f2 __attribute__((ext_vector_type(2)));

template <int N>
__device__ __forceinline__ int rorki_(int v) {           // row_ror:N (16-lane rows)
    return __builtin_amdgcn_update_dpp(v, v, 0x120 + N, 0xf, 0xf, true);
}
template <int N>
__device__ __forceinline__ float rorkf_(float v) { return __int_as_float(rorki_<N>(__float_as_int(v))); }
template <int C>
__device__ __forceinline__ float shrf_(float v) {        // row_shr:N, shifted-in -> 0
    return __int_as_float(__builtin_amdgcn_update_dpp(0, __float_as_int(v), C, 0xf, 0xf, true));
}
__device__ __forceinline__ float sgm_(float v) {         // sigmoid, arg pre-scaled by log2e
    return __builtin_amdgcn_rcpf(1.f + __builtin_amdgcn_exp2f(-v));
}
__device__ __forceinline__ f2 pfma_(f2 a, f2 b, f2 c) {  // v_pk_fma_f32
    return __builtin_elementwise_fma(a, b, c);
}

__launch_bounds__(128)
__attribute__((amdgpu_waves_per_eu(2, 2)))   // exactly 2 waves/EU -> 256-VGPR budget
__global__ void gru_ws8(const float* __restrict__ x,
                        const float* __restrict__ W1, const float* __restrict__ Ur1,
                        const float* __restrict__ b1,
                        const float* __restrict__ W2, const float* __restrict__ Ur2,
                        const float* __restrict__ b2,
                        const float* __restrict__ Wd, const float* __restrict__ bd,
                        const float* __restrict__ Wo, const float* __restrict__ bo,
                        float* __restrict__ out)
{
    // Feed-forward buffers only; producer/consumer separated by >=1 phase + barrier.
    __shared__ float h1b[2][CH][4][8];
    __shared__ float h2b[2][CH][4][16];

    const int tid  = threadIdx.x;
    const int wv   = tid >> 6;          // 0: GRU1+dense, 1: GRU2
    const int lane = tid & 63;
    const int g    = lane >> 4;         // row group (4 rows/block)
    const int j    = lane & 15;
    const int u1   = j & 7;
    const int hi   = j >> 3;
    const int gcol = u1 + 8 * hi;
    const bool ishi = (hi != 0);
    const bool isw  = (j == 15);

    // ---- trace the ror:k permutation (layout-proof rotation weight order) ----
    int Lk[16];
    Lk[0]  = j;
    Lk[1]  = rorki_<1>(j);   Lk[2]  = rorki_<2>(j);   Lk[3]  = rorki_<3>(j);
    Lk[4]  = rorki_<4>(j);   Lk[5]  = rorki_<5>(j);   Lk[6]  = rorki_<6>(j);
    Lk[7]  = rorki_<7>(j);   Lk[8]  = rorki_<8>(j);   Lk[9]  = rorki_<9>(j);
    Lk[10] = rorki_<10>(j);  Lk[11] = rorki_<11>(j);  Lk[12] = rorki_<12>(j);
    Lk[13] = rorki_<13>(j);  Lk[14] = rorki_<14>(j);  Lk[15] = rorki_<15>(j);

    if (wv == 0) {
        // ================= wave A: GRU1 (in-register) + dense (h2 from LDS) =====
        f2 Gx[4], Hx[4], VC[4], VQ[4];          // rotation-ordered GRU1 taps
#pragma unroll
        for (int k = 0; k < 4; ++k) {
            const int a = Lk[2 * k] & 7, b = Lk[2 * k + 1] & 7;
            Gx[k] = f2{LOG2E * W1[a * 24 + gcol],  LOG2E * W1[b * 24 + gcol]};
            Hx[k] = f2{W1[a * 24 + 16 + u1],       W1[b * 24 + 16 + u1]};
            VC[k] = f2{LOG2E * Ur1[a * 24 + gcol], LOG2E * Ur1[b * 24 + gcol]};
            VQ[k] = f2{Ur1[a * 24 + 16 + u1],      Ur1[b * 24 + 16 + u1]};
        }
        f2 Pd[8];                               // dense taps, NATURAL order (h2 from LDS)
#pragma unroll
        for (int k = 0; k < 8; ++k)
            Pd[k] = f2{Wd[(2 * k) * 16 + j], Wd[(2 * k + 1) * 16 + j]};
        const float bAzr = LOG2E * (b1[gcol] + b1[24 + gcol]);
        const float bGh  = b1[16 + u1];
        const float bIh  = b1[40 + u1];
        const float bdj  = bd[j], woj = Wo[j], boo = bo[0];

        const float* xbase = x + (size_t)blockIdx.x * 4 * TT * 8;
        const int    xoff  = g * TT * 8 + u1;
        float* outrow = out + (size_t)(blockIdx.x * 4 + g) * TT;

        float h1own = 0.f, azrP = bAzr, ihP = bIh;
        // 8-deep x register queue: covers ~1600 cyc of load latency (HBM worst case)
        float x0 = xbase[0 * 8 + xoff];
        float x1 = xbase[1 * 8 + xoff];
        float x2 = xbase[2 * 8 + xoff];
        float x3 = xbase[3 * 8 + xoff];
        float x4 = xbase[4 * 8 + xoff];
        float x5 = xbase[5 * 8 + xoff];
        float x6 = xbase[6 * 8 + xoff];
        float x7 = xbase[7 * 8 + xoff];
        float4 hA0, hA1, hA2, hA3, hB0, hB1, hB2, hB3;   // dense ping-pong

#define G1STEP(TG, SL, XSLOT)                                                \
    {                                                                        \
        const float xc = XSLOT;                                              \
        const f2 xp0 = f2{xc,            rorkf_<1>(xc)};                     \
        const f2 xp1 = f2{rorkf_<2>(xc), rorkf_<3>(xc)};                     \
        const f2 xp2 = f2{rorkf_<4>(xc), rorkf_<5>(xc)};                     \
        const f2 xp3 = f2{rorkf_<6>(xc), rorkf_<7>(xc)};                     \
        f2 axp = f2{azrP, 0.f}, ghp = f2{bGh, 0.f};                          \
        axp = pfma_(xp0, Gx[0], axp);  ghp = pfma_(xp0, Hx[0], ghp);         \
        axp = pfma_(xp1, Gx[1], axp);  ghp = pfma_(xp1, Hx[1], ghp);         \
        axp = pfma_(xp2, Gx[2], axp);  ghp = pfma_(xp2, Hx[2], ghp);         \
        axp = pfma_(xp3, Gx[3], axp);  ghp = pfma_(xp3, Hx[3], ghp);         \
        XSLOT = xbase[(((TG) + 8) & (TT - 1)) * 8 + xoff];  /* refill s+8 */ \
        const float azrC = axp.x + axp.y;                                    \
        const float s_own = sgm_(azrC);                                      \
        const float s_sw  = rorkf_<8>(s_own);                                \
        const float z1 = ishi ? s_sw : s_own;                                \
        const float r1 = ishi ? s_own : s_sw;                                \
        const float hh1 = fmaxf(fmaf(r1, ihP, ghp.x + ghp.y), 0.f);          \
        h1own = fmaf(z1, h1own - hh1, hh1);                                  \
        const float n0 = h1own;                                              \
        const f2 np0 = f2{n0,            rorkf_<1>(n0)};                     \
        const f2 np1 = f2{rorkf_<2>(n0), rorkf_<3>(n0)};                     \
        const f2 np2 = f2{rorkf_<4>(n0), rorkf_<5>(n0)};                     \
        const f2 np3 = f2{rorkf_<6>(n0), rorkf_<7>(n0)};                     \
        f2 aNp = f2{bAzr, 0.f}, iNp = f2{bIh, 0.f};                          \
        aNp = pfma_(np0, VC[0], aNp);  iNp = pfma_(np0, VQ[0], iNp);         \
        aNp = pfma_(np1, VC[1], aNp);  iNp = pfma_(np1, VQ[1], iNp);         \
        aNp = pfma_(np2, VC[2], aNp);  iNp = pfma_(np2, VQ[2], iNp);         \
        aNp = pfma_(np3, VC[3], aNp);  iNp = pfma_(np3, VQ[3], iNp);         \
        azrP = aNp.x + aNp.y;  ihP = iNp.x + iNp.y;                          \
        h1b[p & 1][SL][g][u1] = h1own;                                       \
    }

#define DSTEP(DL, C0, C1, C2, C3, N0, N1, N2, N3, DN)                        \
    {                                                                        \
        f2 da = f2{bdj, 0.f};                                                \
        da = pfma_(f2{C0.x, C0.y}, Pd[0], da);                               \
        da = pfma_(f2{C0.z, C0.w}, Pd[1], da);                               \
        da = pfma_(f2{C1.x, C1.y}, Pd[2], da);                               \
        da = pfma_(f2{C1.z, C1.w}, Pd[3], da);                               \
        da = pfma_(f2{C2.x, C2.y}, Pd[4], da);                               \
        da = pfma_(f2{C2.z, C2.w}, Pd[5], da);                               \
        da = pfma_(f2{C3.x, C3.y}, Pd[6], da);                               \
        da = pfma_(f2{C3.z, C3.w}, Pd[7], da);                               \
        N0 = *(const float4*)&h2b[p & 1][DN][g][0];                          \
        N1 = *(const float4*)&h2b[p & 1][DN][g][4];                          \
        N2 = *(const float4*)&h2b[p & 1][DN][g][8];                          \
        N3 = *(const float4*)&h2b[p & 1][DN][g][12];                         \
        float e = fmaxf(da.x + da.y, 0.f) * woj;                             \
        e += shrf_<0x118>(e);                                                \
        e += shrf_<0x114>(e);                                                \
        e += shrf_<0x112>(e);                                                \
        e += shrf_<0x111>(e);                                                \
        if (isw) outd[DL] = e + boo;                                         \
    }

        for (int p = 0; p < NPH; ++p) {
            if (p < 2) {
                const int t0 = p * CH;
                for (int s = 0; s < CH; s += 8) {
                    G1STEP(t0 + s + 0, s + 0, x0)
                    G1STEP(t0 + s + 1, s + 1, x1)
                    G1STEP(t0 + s + 2, s + 2, x2)
                    G1STEP(t0 + s + 3, s + 3, x3)
                    G1STEP(t0 + s + 4, s + 4, x4)
                    G1STEP(t0 + s + 5, s + 5, x5)
                    G1STEP(t0 + s + 6, s + 6, x6)
                    G1STEP(t0 + s + 7, s + 7, x7)
                }
            } else if (p < NCH) {
                const int t0 = p * CH;
                float* outd = outrow + (p - 2) * CH;
                hA0 = *(const float4*)&h2b[p & 1][0][g][0];
                hA1 = *(const float4*)&h2b[p & 1][0][g][4];
                hA2 = *(const float4*)&h2b[p & 1][0][g][8];
                hA3 = *(const float4*)&h2b[p & 1][0][g][12];
                for (int s = 0; s < CH; s += 8) {
                    G1STEP(t0 + s + 0, s + 0, x0)
                    DSTEP(s + 0, hA0, hA1, hA2, hA3, hB0, hB1, hB2, hB3, s + 1)
                    G1STEP(t0 + s + 1, s + 1, x1)
                    DSTEP(s + 1, hB0, hB1, hB2, hB3, hA0, hA1, hA2, hA3, s + 2)
                    G1STEP(t0 + s + 2, s + 2, x2)
                    DSTEP(s + 2, hA0, hA1, hA2, hA3, hB0, hB1, hB2, hB3, s + 3)
                    G1STEP(t0 + s + 3, s + 3, x3)
                    DSTEP(s + 3, hB0, hB1, hB2, hB3, hA0, hA1, hA2, hA3, s + 4)
                    G1STEP(t0 + s + 4, s + 4, x4)
                    DSTEP(s + 4, hA0, hA1, hA2, hA3, hB0, hB1, hB2, hB3, s + 5)
                    G1STEP(t0 + s + 5, s + 5, x5)
                    DSTEP(s + 5, hB0, hB1, hB2, hB3, hA0, hA1, hA2, hA3, s + 6)
                    G1STEP(t0 + s + 6, s + 6, x6)
                    DSTEP(s + 6, hA0, hA1, hA2, hA3, hB0, hB1, hB2, hB3, s + 7)
                    G1STEP(t0 + s + 7, s + 7, x7)
                    DSTEP(s + 7, hB0, hB1, hB2, hB3, hA0, hA1, hA2, hA3, (s + 8) & (CH - 1))
                }
            } else {
                float* outd = outrow + (p - 2) * CH;
                hA0 = *(const float4*)&h2b[p & 1][0][g][0];
                hA1 = *(const float4*)&h2b[p & 1][0][g][4];
                hA2 = *(const float4*)&h2b[p & 1][0][g][8];
                hA3 = *(const float4*)&h2b[p & 1][0][g][12];
                for (int s = 0; s < CH; s += 4) {
                    DSTEP(s + 0, hA0, hA1, hA2, hA3, hB0, hB1, hB2, hB3, s + 1)
                    DSTEP(s + 1, hB0, hB1, hB2, hB3, hA0, hA1, hA2, hA3, s + 2)
                    DSTEP(s + 2, hA0, hA1, hA2, hA3, hB0, hB1, hB2, hB3, s + 3)
                    DSTEP(s + 3, hB0, hB1, hB2, hB3, hA0, hA1, hA2, hA3, (s + 4) & (CH - 1))
                }
            }
            __syncthreads();
        }
#undef G1STEP
#undef DSTEP
    } else {
        // ================= wave B: GRU2 (in-register; h1 from LDS, natural order) =====
        f2 Pz[8], Pr[8], Ph[8];                 // h2 fan, rotation-ordered
#pragma unroll
        for (int k = 0; k < 8; ++k) {
            const int a = Lk[2 * k], b = Lk[2 * k + 1];
            Pz[k] = f2{LOG2E * Ur2[a * 48 + j],      LOG2E * Ur2[b * 48 + j]};
            Pr[k] = f2{LOG2E * Ur2[a * 48 + 16 + j], LOG2E * Ur2[b * 48 + 16 + j]};
            Ph[k] = f2{Ur2[a * 48 + 32 + j],         Ur2[b * 48 + 32 + j]};
        }
        f2 Vz[4], Vr[4], Vh[4];                 // W2 taps, NATURAL order
#pragma unroll
        for (int k = 0; k < 4; ++k) {
            Vz[k] = f2{LOG2E * W2[(2 * k) * 48 + j],      LOG2E * W2[(2 * k + 1) * 48 + j]};
            Vr[k] = f2{LOG2E * W2[(2 * k) * 48 + 16 + j], LOG2E * W2[(2 * k + 1) * 48 + 16 + j]};
            Vh[k] = f2{W2[(2 * k) * 48 + 32 + j],         W2[(2 * k + 1) * 48 + 32 + j]};
        }
        const float bA2 = LOG2E * (b2[j] + b2[48 + j]);
        const float bB2 = LOG2E * (b2[16 + j] + b2[64 + j]);
        const float bC2 = b2[80 + j];
        const float bD2 = b2[32 + j];

        float h2own = 0.f;
        float4 kA0, kA1, kB0, kB1;              // h1 ping-pong

#define G2STEP(SL, K0, K1, M0, M1, SN)                                       \
    {                                                                        \
        const float h0 = h2own;                                              \
        const f2 tp0 = f2{h0,             rorkf_<1>(h0)};                    \
        const f2 tp1 = f2{rorkf_<2>(h0),  rorkf_<3>(h0)};                    \
        const f2 tp2 = f2{rorkf_<4>(h0),  rorkf_<5>(h0)};                    \
        const f2 tp3 = f2{rorkf_<6>(h0),  rorkf_<7>(h0)};                    \
        const f2 tp4 = f2{rorkf_<8>(h0),  rorkf_<9>(h0)};                    \
        const f2 tp5 = f2{rorkf_<10>(h0), rorkf_<11>(h0)};                   \
        const f2 tp6 = f2{rorkf_<12>(h0), rorkf_<13>(h0)};                   \
        const f2 tp7 = f2{rorkf_<14>(h0), rorkf_<15>(h0)};                   \
        f2 za = f2{bA2, 0.f}, ra = f2{bB2, 0.f}, ha = f2{bC2, 0.f};          \
        za = pfma_(tp0, Pz[0], za); ra = pfma_(tp0, Pr[0], ra); ha = pfma_(tp0, Ph[0], ha); \
        za = pfma_(tp1, Pz[1], za); ra = pfma_(tp1, Pr[1], ra); ha = pfma_(tp1, Ph[1], ha); \
        za = pfma_(tp2, Pz[2], za); ra = pfma_(tp2, Pr[2], ra); ha = pfma_(tp2, Ph[2], ha); \
        za = pfma_(tp3, Pz[3], za); ra = pfma_(tp3, Pr[3], ra); ha = pfma_(tp3, Ph[3], ha); \
        za = pfma_(tp4, Pz[4], za); ra = pfma_(tp4, Pr[4], ra); ha = pfma_(tp4, Ph[4], ha); \
        za = pfma_(tp5, Pz[5], za); ra = pfma_(tp5, Pr[5], ra); ha = pfma_(tp5, Ph[5], ha); \
        za = pfma_(tp6, Pz[6], za); ra = pfma_(tp6, Pr[6], ra); ha = pfma_(tp6, Ph[6], ha); \
        za = pfma_(tp7, Pz[7], za); ra = pfma_(tp7, Pr[7], ra); ha = pfma_(tp7, Ph[7], ha); \
        const f2 q0 = f2{K0.x, K0.y}, q1 = f2{K0.z, K0.w};                   \
        const f2 q2 = f2{K1.x, K1.y}, q3 = f2{K1.z, K1.w};                   \
        f2 hbp = f2{bD2, 0.f};                                               \
        za = pfma_(q0, Vz[0], za); ra = pfma_(q0, Vr[0], ra); hbp = pfma_(q0, Vh[0], hbp); \
        za = pfma_(q1, Vz[1], za); ra = pfma_(q1, Vr[1], ra); hbp = pfma_(q1, Vh[1], hbp); \
        za = pfma_(q2, Vz[2], za); ra = pfma_(q2, Vr[2], ra); hbp = pfma_(q2, Vh[2], hbp); \
        za = pfma_(q3, Vz[3], za); ra = pfma_(q3, Vr[3], ra); hbp = pfma_(q3, Vh[3], hbp); \
        M0 = *(const float4*)&h1b[(p - 1) & 1][SN][g][0];                    \
        M1 = *(const float4*)&h1b[(p - 1) & 1][SN][g][4];                    \
        const float z2 = sgm_(za.x + za.y), r2 = sgm_(ra.x + ra.y);          \
        const float hh2 = fmaxf(fmaf(r2, ha.x + ha.y, hbp.x + hbp.y), 0.f);  \
        h2own = fmaf(z2, h2own - hh2, hh2);                                  \
        h2b[(p - 1) & 1][SL][g][j] = h2own;                                  \
    }

        for (int p = 0; p < NPH; ++p) {
            if (p >= 1 && p <= NCH) {
                kA0 = *(const float4*)&h1b[(p - 1) & 1][0][g][0];
                kA1 = *(const float4*)&h1b[(p - 1) & 1][0][g][4];
                for (int s = 0; s < CH; s += 2) {
                    G2STEP(s + 0, kA0, kA1, kB0, kB1, s + 1)
                    G2STEP(s + 1, kB0, kB1, kA0, kA1, (s + 2) & (CH - 1))
                }
            }
            __syncthreads();
        }
#undef G2STEP
    }
}

extern "C" void kernel_launch(void* const* d_in, const int* in_sizes, int n_in,
                              void* d_out, int out_size, void* d_ws, size_t ws_size,
                              hipStream_t stream) {
    const float* x   = (const float*)d_in[0];
    const float* W1  = (const float*)d_in[1];
    const float* Ur1 = (const float*)d_in[2];
    const float* b1  = (const float*)d_in[3];
    const float* W2  = (const float*)d_in[4];
    const float* Ur2 = (const float*)d_in[5];
    const float* b2  = (const float*)d_in[6];
    const float* Wd  = (const float*)d_in[7];
    const float* bd  = (const float*)d_in[8];
    const float* Wo  = (const float*)d_in[9];
    const float* bo  = (const float*)d_in[10];
    float* out = (float*)d_out;

    dim3 grid(4096 / 4);   // 1024 blocks x 2 waves = 2048 waves = 2/SIMD, true split
    dim3 block(128);       // wave 0: GRU1+dense, wave 1: GRU2; 4 rows/block
    gru_ws8<<<grid, block, 0, stream>>>(x, W1, Ur1, b1, W2, Ur2, b2,
                                        Wd, bd, Wo, bo, out);
}

// Round 19
// 157.081 us; speedup vs baseline: 1.1894x; 1.0499x over previous
//
#include <hip/hip_runtime.h>

#define TT 512
#define CH 32
#define NCH 16            // 512/32 chunks
#define NPH (NCH + 2)     // phases: A leads, dense trails by 2
#define LOG2E 1.44269504088896340736f

typedef float f2 __attribute__((ext_vector_type(2)));

template <int N>
__device__ __forceinline__ int rorki_(int v) {           // row_ror:N (16-lane rows)
    return __builtin_amdgcn_update_dpp(v, v, 0x120 + N, 0xf, 0xf, true);
}
template <int N>
__device__ __forceinline__ float rorkf_(float v) { return __int_as_float(rorki_<N>(__float_as_int(v))); }
template <int C>
__device__ __forceinline__ float shrf_(float v) {        // row_shr:N, shifted-in -> 0
    return __int_as_float(__builtin_amdgcn_update_dpp(0, __float_as_int(v), C, 0xf, 0xf, true));
}
__device__ __forceinline__ float sgm_(float v) {         // sigmoid, arg pre-scaled by log2e
    return __builtin_amdgcn_rcpf(1.f + __builtin_amdgcn_exp2f(-v));
}
__device__ __forceinline__ f2 pfma_(f2 a, f2 b, f2 c) {  // v_pk_fma_f32
    return __builtin_elementwise_fma(a, b, c);
}

__launch_bounds__(128)
__attribute__((amdgpu_waves_per_eu(2, 2)))   // exactly 2 waves/EU -> 256-VGPR budget
__global__ void gru_wsp(const float* __restrict__ x,
                        const float* __restrict__ W1, const float* __restrict__ Ur1,
                        const float* __restrict__ b1,
                        const float* __restrict__ W2, const float* __restrict__ Ur2,
                        const float* __restrict__ b2,
                        const float* __restrict__ Wd, const float* __restrict__ bd,
                        const float* __restrict__ Wo, const float* __restrict__ bo,
                        float* __restrict__ out)
{
    // Feed-forward buffers only; producer/consumer separated by >=1 phase + barrier.
    __shared__ float h1b[2][CH][4][8];
    __shared__ float h2b[2][CH][4][16];

    const int tid  = threadIdx.x;
    const int wv   = tid >> 6;          // 0: GRU1+dense, 1: GRU2
    const int lane = tid & 63;
    const int g    = lane >> 4;         // row group (4 rows/block)
    const int j    = lane & 15;
    const int u1   = j & 7;
    const int hi   = j >> 3;
    const int gcol = u1 + 8 * hi;
    const bool ishi = (hi != 0);
    const bool isw  = (j == 15);

    // ---- trace the ror:k permutation (layout-proof rotation weight order) ----
    int Lk[16];
    Lk[0]  = j;
    Lk[1]  = rorki_<1>(j);   Lk[2]  = rorki_<2>(j);   Lk[3]  = rorki_<3>(j);
    Lk[4]  = rorki_<4>(j);   Lk[5]  = rorki_<5>(j);   Lk[6]  = rorki_<6>(j);
    Lk[7]  = rorki_<7>(j);   Lk[8]  = rorki_<8>(j);   Lk[9]  = rorki_<9>(j);
    Lk[10] = rorki_<10>(j);  Lk[11] = rorki_<11>(j);  Lk[12] = rorki_<12>(j);
    Lk[13] = rorki_<13>(j);  Lk[14] = rorki_<14>(j);  Lk[15] = rorki_<15>(j);

    if (wv == 0) {
        // ================= wave A: GRU1 (in-register) + dense (h2 from LDS) =====
        f2 Gx[4], Hx[4], VC[4], VQ[4];          // rotation-ordered GRU1 taps
#pragma unroll
        for (int k = 0; k < 4; ++k) {
            const int a = Lk[2 * k] & 7, b = Lk[2 * k + 1] & 7;
            Gx[k] = f2{LOG2E * W1[a * 24 + gcol],  LOG2E * W1[b * 24 + gcol]};
            Hx[k] = f2{W1[a * 24 + 16 + u1],       W1[b * 24 + 16 + u1]};
            VC[k] = f2{LOG2E * Ur1[a * 24 + gcol], LOG2E * Ur1[b * 24 + gcol]};
            VQ[k] = f2{Ur1[a * 24 + 16 + u1],      Ur1[b * 24 + 16 + u1]};
        }
        f2 Pd[8];                               // dense taps, NATURAL order (h2 from LDS)
#pragma unroll
        for (int k = 0; k < 8; ++k)
            Pd[k] = f2{Wd[(2 * k) * 16 + j], Wd[(2 * k + 1) * 16 + j]};
        const float bAzr = LOG2E * (b1[gcol] + b1[24 + gcol]);
        const float bGh  = b1[16 + u1];
        const float bIh  = b1[40 + u1];
        const float bdj  = bd[j], woj = Wo[j], boo = bo[0];

        const float* xbase = x + (size_t)blockIdx.x * 4 * TT * 8;
        const int    xoff  = g * TT * 8 + u1;
        float* outrow = out + (size_t)(blockIdx.x * 4 + g) * TT;

        float h1own = 0.f, azrP = bAzr, ihP = bIh;
        // 8-deep x register queue (R18-proven, neutral-or-better)
        float x0 = xbase[0 * 8 + xoff];
        float x1 = xbase[1 * 8 + xoff];
        float x2 = xbase[2 * 8 + xoff];
        float x3 = xbase[3 * 8 + xoff];
        float x4 = xbase[4 * 8 + xoff];
        float x5 = xbase[5 * 8 + xoff];
        float x6 = xbase[6 * 8 + xoff];
        float x7 = xbase[7 * 8 + xoff];
        float4 hA0, hA1, hA2, hA3, hB0, hB1, hB2, hB3;   // dense ping-pong

#define G1STEP(TG, SL, XSLOT)                                                \
    {                                                                        \
        const float xc = XSLOT;                                              \
        const f2 xp0 = f2{xc,            rorkf_<1>(xc)};                     \
        const f2 xp1 = f2{rorkf_<2>(xc), rorkf_<3>(xc)};                     \
        const f2 xp2 = f2{rorkf_<4>(xc), rorkf_<5>(xc)};                     \
        const f2 xp3 = f2{rorkf_<6>(xc), rorkf_<7>(xc)};                     \
        f2 axp = f2{azrP, 0.f}, ghp = f2{bGh, 0.f};                          \
        axp = pfma_(xp0, Gx[0], axp);  ghp = pfma_(xp0, Hx[0], ghp);         \
        axp = pfma_(xp1, Gx[1], axp);  ghp = pfma_(xp1, Hx[1], ghp);         \
        axp = pfma_(xp2, Gx[2], axp);  ghp = pfma_(xp2, Hx[2], ghp);         \
        axp = pfma_(xp3, Gx[3], axp);  ghp = pfma_(xp3, Hx[3], ghp);         \
        XSLOT = xbase[(((TG) + 8) & (TT - 1)) * 8 + xoff];  /* refill s+8 */ \
        const float azrC = axp.x + axp.y;                                    \
        const float s_own = sgm_(azrC);                                      \
        const float s_sw  = rorkf_<8>(s_own);                                \
        const float z1 = ishi ? s_sw : s_own;                                \
        const float r1 = ishi ? s_own : s_sw;                                \
        const float hh1 = fmaxf(fmaf(r1, ihP, ghp.x + ghp.y), 0.f);          \
        h1own = fmaf(z1, h1own - hh1, hh1);                                  \
        const float n0 = h1own;                                              \
        const f2 np0 = f2{n0,            rorkf_<1>(n0)};                     \
        const f2 np1 = f2{rorkf_<2>(n0), rorkf_<3>(n0)};                     \
        const f2 np2 = f2{rorkf_<4>(n0), rorkf_<5>(n0)};                     \
        const f2 np3 = f2{rorkf_<6>(n0), rorkf_<7>(n0)};                     \
        f2 aNp = f2{bAzr, 0.f}, iNp = f2{bIh, 0.f};                          \
        aNp = pfma_(np0, VC[0], aNp);  iNp = pfma_(np0, VQ[0], iNp);         \
        aNp = pfma_(np1, VC[1], aNp);  iNp = pfma_(np1, VQ[1], iNp);         \
        aNp = pfma_(np2, VC[2], aNp);  iNp = pfma_(np2, VQ[2], iNp);         \
        aNp = pfma_(np3, VC[3], aNp);  iNp = pfma_(np3, VQ[3], iNp);         \
        azrP = aNp.x + aNp.y;  ihP = iNp.x + iNp.y;                          \
        h1b[p & 1][SL][g][u1] = h1own;                                       \
    }

#define DSTEP(DL, C0, C1, C2, C3, N0, N1, N2, N3, DN)                        \
    {                                                                        \
        f2 da = f2{bdj, 0.f};                                                \
        da = pfma_(f2{C0.x, C0.y}, Pd[0], da);                               \
        da = pfma_(f2{C0.z, C0.w}, Pd[1], da);                               \
        da = pfma_(f2{C1.x, C1.y}, Pd[2], da);                               \
        da = pfma_(f2{C1.z, C1.w}, Pd[3], da);                               \
        da = pfma_(f2{C2.x, C2.y}, Pd[4], da);                               \
        da = pfma_(f2{C2.z, C2.w}, Pd[5], da);                               \
        da = pfma_(f2{C3.x, C3.y}, Pd[6], da);                               \
        da = pfma_(f2{C3.z, C3.w}, Pd[7], da);                               \
        N0 = *(const float4*)&h2b[p & 1][DN][g][0];                          \
        N1 = *(const float4*)&h2b[p & 1][DN][g][4];                          \
        N2 = *(const float4*)&h2b[p & 1][DN][g][8];                          \
        N3 = *(const float4*)&h2b[p & 1][DN][g][12];                         \
        float e = fmaxf(da.x + da.y, 0.f) * woj;                             \
        e += shrf_<0x118>(e);                                                \
        e += shrf_<0x114>(e);                                                \
        e += shrf_<0x112>(e);                                                \
        e += shrf_<0x111>(e);                                                \
        if (isw) outd[DL] = e + boo;                                         \
    }

        for (int p = 0; p < NPH; ++p) {
            if (p < 2) {
                const int t0 = p * CH;
                for (int s = 0; s < CH; s += 8) {
                    G1STEP(t0 + s + 0, s + 0, x0)
                    G1STEP(t0 + s + 1, s + 1, x1)
                    G1STEP(t0 + s + 2, s + 2, x2)
                    G1STEP(t0 + s + 3, s + 3, x3)
                    G1STEP(t0 + s + 4, s + 4, x4)
                    G1STEP(t0 + s + 5, s + 5, x5)
                    G1STEP(t0 + s + 6, s + 6, x6)
                    G1STEP(t0 + s + 7, s + 7, x7)
                }
            } else if (p < NCH) {
                const int t0 = p * CH;
                float* outd = outrow + (p - 2) * CH;
                hA0 = *(const float4*)&h2b[p & 1][0][g][0];
                hA1 = *(const float4*)&h2b[p & 1][0][g][4];
                hA2 = *(const float4*)&h2b[p & 1][0][g][8];
                hA3 = *(const float4*)&h2b[p & 1][0][g][12];
                for (int s = 0; s < CH; s += 8) {
                    G1STEP(t0 + s + 0, s + 0, x0)
                    DSTEP(s + 0, hA0, hA1, hA2, hA3, hB0, hB1, hB2, hB3, s + 1)
                    G1STEP(t0 + s + 1, s + 1, x1)
                    DSTEP(s + 1, hB0, hB1, hB2, hB3, hA0, hA1, hA2, hA3, s + 2)
                    G1STEP(t0 + s + 2, s + 2, x2)
                    DSTEP(s + 2, hA0, hA1, hA2, hA3, hB0, hB1, hB2, hB3, s + 3)
                    G1STEP(t0 + s + 3, s + 3, x3)
                    DSTEP(s + 3, hB0, hB1, hB2, hB3, hA0, hA1, hA2, hA3, s + 4)
                    G1STEP(t0 + s + 4, s + 4, x4)
                    DSTEP(s + 4, hA0, hA1, hA2, hA3, hB0, hB1, hB2, hB3, s + 5)
                    G1STEP(t0 + s + 5, s + 5, x5)
                    DSTEP(s + 5, hB0, hB1, hB2, hB3, hA0, hA1, hA2, hA3, s + 6)
                    G1STEP(t0 + s + 6, s + 6, x6)
                    DSTEP(s + 6, hA0, hA1, hA2, hA3, hB0, hB1, hB2, hB3, s + 7)
                    G1STEP(t0 + s + 7, s + 7, x7)
                    DSTEP(s + 7, hB0, hB1, hB2, hB3, hA0, hA1, hA2, hA3, (s + 8) & (CH - 1))
                }
            } else {
                float* outd = outrow + (p - 2) * CH;
                hA0 = *(const float4*)&h2b[p & 1][0][g][0];
                hA1 = *(const float4*)&h2b[p & 1][0][g][4];
                hA2 = *(const float4*)&h2b[p & 1][0][g][8];
                hA3 = *(const float4*)&h2b[p & 1][0][g][12];
                for (int s = 0; s < CH; s += 4) {
                    DSTEP(s + 0, hA0, hA1, hA2, hA3, hB0, hB1, hB2, hB3, s + 1)
                    DSTEP(s + 1, hB0, hB1, hB2, hB3, hA0, hA1, hA2, hA3, s + 2)
                    DSTEP(s + 2, hA0, hA1, hA2, hA3, hB0, hB1, hB2, hB3, s + 3)
                    DSTEP(s + 3, hB0, hB1, hB2, hB3, hA0, hA1, hA2, hA3, (s + 4) & (CH - 1))
                }
            }
            __syncthreads();
        }
#undef G1STEP
#undef DSTEP
    } else {
        // ================= wave B: GRU2 (critical wave; runs at priority 1) =====
        __builtin_amdgcn_s_setprio(1);          // favor the recurrence-critical wave
        f2 Pz[8], Pr[8], Ph[8];                 // h2 fan, rotation-ordered
#pragma unroll
        for (int k = 0; k < 8; ++k) {
            const int a = Lk[2 * k], b = Lk[2 * k + 1];
            Pz[k] = f2{LOG2E * Ur2[a * 48 + j],      LOG2E * Ur2[b * 48 + j]};
            Pr[k] = f2{LOG2E * Ur2[a * 48 + 16 + j], LOG2E * Ur2[b * 48 + 16 + j]};
            Ph[k] = f2{Ur2[a * 48 + 32 + j],         Ur2[b * 48 + 32 + j]};
        }
        f2 Vz[4], Vr[4], Vh[4];                 // W2 taps, NATURAL order
#pragma unroll
        for (int k = 0; k < 4; ++k) {
            Vz[k] = f2{LOG2E * W2[(2 * k) * 48 + j],      LOG2E * W2[(2 * k + 1) * 48 + j]};
            Vr[k] = f2{LOG2E * W2[(2 * k) * 48 + 16 + j], LOG2E * W2[(2 * k + 1) * 48 + 16 + j]};
            Vh[k] = f2{W2[(2 * k) * 48 + 32 + j],         W2[(2 * k + 1) * 48 + 32 + j]};
        }
        const float bA2 = LOG2E * (b2[j] + b2[48 + j]);
        const float bB2 = LOG2E * (b2[16 + j] + b2[64 + j]);
        const float bC2 = b2[80 + j];
        const float bD2 = b2[32 + j];

        float h2own = 0.f;
        float4 kA0, kA1, kB0, kB1;              // h1 ping-pong

#define G2STEP(SL, K0, K1, M0, M1, SN)                                       \
    {                                                                        \
        const float h0 = h2own;                                              \
        const f2 tp0 = f2{h0,             rorkf_<1>(h0)};                    \
        const f2 tp1 = f2{rorkf_<2>(h0),  rorkf_<3>(h0)};                    \
        const f2 tp2 = f2{rorkf_<4>(h0),  rorkf_<5>(h0)};                    \
        const f2 tp3 = f2{rorkf_<6>(h0),  rorkf_<7>(h0)};                    \
        const f2 tp4 = f2{rorkf_<8>(h0),  rorkf_<9>(h0)};                    \
        const f2 tp5 = f2{rorkf_<10>(h0), rorkf_<11>(h0)};                   \
        const f2 tp6 = f2{rorkf_<12>(h0), rorkf_<13>(h0)};                   \
        const f2 tp7 = f2{rorkf_<14>(h0), rorkf_<15>(h0)};                   \
        f2 za = f2{bA2, 0.f}, ra = f2{bB2, 0.f}, ha = f2{bC2, 0.f};          \
        za = pfma_(tp0, Pz[0], za); ra = pfma_(tp0, Pr[0], ra); ha = pfma_(tp0, Ph[0], ha); \
        za = pfma_(tp1, Pz[1], za); ra = pfma_(tp1, Pr[1], ra); ha = pfma_(tp1, Ph[1], ha); \
        za = pfma_(tp2, Pz[2], za); ra = pfma_(tp2, Pr[2], ra); ha = pfma_(tp2, Ph[2], ha); \
        za = pfma_(tp3, Pz[3], za); ra = pfma_(tp3, Pr[3], ra); ha = pfma_(tp3, Ph[3], ha); \
        za = pfma_(tp4, Pz[4], za); ra = pfma_(tp4, Pr[4], ra); ha = pfma_(tp4, Ph[4], ha); \
        za = pfma_(tp5, Pz[5], za); ra = pfma_(tp5, Pr[5], ra); ha = pfma_(tp5, Ph[5], ha); \
        za = pfma_(tp6, Pz[6], za); ra = pfma_(tp6, Pr[6], ra); ha = pfma_(tp6, Ph[6], ha); \
        za = pfma_(tp7, Pz[7], za); ra = pfma_(tp7, Pr[7], ra); ha = pfma_(tp7, Ph[7], ha); \
        const f2 q0 = f2{K0.x, K0.y}, q1 = f2{K0.z, K0.w};                   \
        const f2 q2 = f2{K1.x, K1.y}, q3 = f2{K1.z, K1.w};                   \
        f2 hbp = f2{bD2, 0.f};                                               \
        za = pfma_(q0, Vz[0], za); ra = pfma_(q0, Vr[0], ra); hbp = pfma_(q0, Vh[0], hbp); \
        za = pfma_(q1, Vz[1], za); ra = pfma_(q1, Vr[1], ra); hbp = pfma_(q1, Vh[1], hbp); \
        za = pfma_(q2, Vz[2], za); ra = pfma_(q2, Vr[2], ra); hbp = pfma_(q2, Vh[2], hbp); \
        za = pfma_(q3, Vz[3], za); ra = pfma_(q3, Vr[3], ra); hbp = pfma_(q3, Vh[3], hbp); \
        M0 = *(const float4*)&h1b[(p - 1) & 1][SN][g][0];                    \
        M1 = *(const float4*)&h1b[(p - 1) & 1][SN][g][4];                    \
        const float z2 = sgm_(za.x + za.y), r2 = sgm_(ra.x + ra.y);          \
        const float hh2 = fmaxf(fmaf(r2, ha.x + ha.y, hbp.x + hbp.y), 0.f);  \
        h2own = fmaf(z2, h2own - hh2, hh2);                                  \
        h2b[(p - 1) & 1][SL][g][j] = h2own;                                  \
    }

        for (int p = 0; p < NPH; ++p) {
            if (p >= 1 && p <= NCH) {
                kA0 = *(const float4*)&h1b[(p - 1) & 1][0][g][0];
                kA1 = *(const float4*)&h1b[(p - 1) & 1][0][g][4];
                for (int s = 0; s < CH; s += 2) {
                    G2STEP(s + 0, kA0, kA1, kB0, kB1, s + 1)
                    G2STEP(s + 1, kB0, kB1, kA0, kA1, (s + 2) & (CH - 1))
                }
            }
            __syncthreads();
        }
        __builtin_amdgcn_s_setprio(0);
#undef G2STEP
    }
}

extern "C" void kernel_launch(void* const* d_in, const int* in_sizes, int n_in,
                              void* d_out, int out_size, void* d_ws, size_t ws_size,
                              hipStream_t stream) {
    const float* x   = (const float*)d_in[0];
    const float* W1  = (const float*)d_in[1];
    const float* Ur1 = (const float*)d_in[2];
    const float* b1  = (const float*)d_in[3];
    const float* W2  = (const float*)d_in[4];
    const float* Ur2 = (const float*)d_in[5];
    const float* b2  = (const float*)d_in[6];
    const float* Wd  = (const float*)d_in[7];
    const float* bd  = (const float*)d_in[8];
    const float* Wo  = (const float*)d_in[9];
    const float* bo  = (const float*)d_in[10];
    float* out = (float*)d_out;

    dim3 grid(4096 / 4);   // 1024 blocks x 2 waves = 2048 waves = 2/SIMD, true split
    dim3 block(128);       // wave 0: GRU1+dense, wave 1: GRU2 (prio 1); 4 rows/block
    gru_wsp<<<grid, block, 0, stream>>>(x, W1, Ur1, b1, W2, Ur2, b2,
                                        Wd, bd, Wo, bo, out);
}